// Round 6
// baseline (229.688 us; speedup 1.0000x reference)
//
#include <hip/hip_runtime.h>

#define NPTS  64
#define NANG  2016          // 64*63/2
#define NCOLS 300000
#define NC4   (NCOLS / 4)   // 75000 float4 columns

typedef float v4 __attribute__((ext_vector_type(4)));

#define PSTR 68             // LDS row stride in floats: 16B-aligned (68*4=272=17*16)

// ---------------------------------------------------------------------------
// Kernel 1: build A^T (mus folded) into d_ws as AT[k*64 + row] = mus[row]*R[row][k]
// (fp32, R3-proven epilogue). Core = R6 segmented structure (passed R3/R5).
//
// R10 post-mortem note (R9/MFMA): apply regressed 52->66us. WRITE_SIZE 75->94MB
// (64B-segment scalar stores from the MFMA C/D layout) and BW dropped; VALUBusy
// fell to 6.7% proving compute was never the bottleneck (true VALU floor ~4us,
// not 16 -- R3 arithmetic error). MFMA reverted; apply goes back to the fully
// coalesced fp32 structure with 4x the blocks for occupancy.
// ---------------------------------------------------------------------------

__device__ __forceinline__ float rl(float x, int lane) {
    return __uint_as_float(__builtin_amdgcn_readlane(__float_as_uint(x), lane));
}

// Groups T..TB-1, exact length 63-T each. S[j] = running[row T+j][col lane].
// Rotation i (1-based) of group T: rows (T, T+i); lane i-1 holds its (c,s).
template<int T, int TB, int TA, int NG>
__device__ __forceinline__ void groups_run(float (&S)[NPTS],
                                           const float (&c)[NG], const float (&s)[NG],
                                           float* __restrict__ slab, int lane)
{
    if constexpr (T < TB) {
        constexpr int g   = T - TA;
        constexpr int LEN = 63 - T;                   // real rotations in group T
        float rt = S[0];
        #pragma unroll
        for (int i = 1; i <= LEN; ++i) {              // compile-time i
            const float cc = rl(c[g], i - 1);         // v_readlane, imm lane
            const float ss = rl(s[g], i - 1);
            const float rb = S[i];
            S[i - 1] = fmaf(ss, rt, cc * rb);         // new row (T+i), pre-shifted
            rt       = fmaf(cc, rt, -ss * rb);        // serial chain
        }
        slab[T * PSTR + lane] = rt;                   // row T of Mw finished
        groups_run<T + 1, TB, TA, NG>(S, c, s, slab, lane);
    }
}

template<int TA, int TB>
__device__ __forceinline__ void do_wave(const float* __restrict__ angles,
                                        float* __restrict__ slab, int lane)
{
    constexpr int NG = TB - TA;
    float c[NG], s[NG];
    #pragma unroll
    for (int g = 0; g < NG; ++g) {                    // all independent -> pipelined
        const int t    = TA + g;
        const int base = 63 * t - (t * (t - 1)) / 2;  // angle base of group t
        float a = 0.0f;
        if (lane < 63 - t) a = angles[base + lane];   // lane i-1 <-> rotation i
        float sv, cv;
        sincosf(a, &sv, &cv);                         // scalar temps: outputs stay
        s[g] = sv; c[g] = cv;                         // promotable to registers
    }

    // segment starts from identity restricted to rows TA..TA+63 (cols<TA: all 0)
    float S[NPTS];
    #pragma unroll
    for (int j = 0; j < NPTS; ++j) S[j] = (TA + j == lane) ? 1.0f : 0.0f;

    groups_run<TA, TB, TA, NG>(S, c, s, slab, lane);

    // rows TB..63 of Mw still live in S[0..63-TB]
    #pragma unroll
    for (int j = 0; j <= 63 - TB; ++j)
        slab[(TB + j) * PSTR + lane] = S[j];
}

// P[rows >= RS] = Ms[RS: , RS:] @ P[RS: , :]; rows < RS of P unchanged.
// k4 starts at RS/4: Ms cols < RS are exact zeros, so partial quads are safe.
template<int RS>
__device__ __forceinline__ void combine_step(float* __restrict__ P,
                                             const float* __restrict__ Ms,
                                             int tid)
{
    const int c4 = tid & 15;                          // v4 column 0..15
    const int rg = tid >> 4;                          // row group 0..15
    constexpr int NR   = 64 - RS;
    constexpr int NIT  = (NR + 15) / 16;
    constexpr int K4_0 = RS / 4;

    v4 acc[NIT];
    #pragma unroll
    for (int it = 0; it < NIT; ++it) acc[it] = (v4)0.0f;

    #pragma unroll 2
    for (int k4 = K4_0; k4 < 16; ++k4) {
        v4 pv[4];
        #pragma unroll
        for (int j = 0; j < 4; ++j)                   // same addr across lanes-of-16:
            pv[j] = *(const v4*)(P + (4 * k4 + j) * PSTR + 4 * c4);   // broadcast
        #pragma unroll
        for (int it = 0; it < NIT; ++it) {
            const int r = RS + rg + 16 * it;
            if (r < 64) {
                const v4 mv = *(const v4*)(Ms + r * PSTR + 4 * k4);
                acc[it] += pv[0] * mv.x;
                acc[it] += pv[1] * mv.y;
                acc[it] += pv[2] * mv.z;
                acc[it] += pv[3] * mv.w;
            }
        }
    }
    __syncthreads();                                  // all reads of P done
    #pragma unroll
    for (int it = 0; it < NIT; ++it) {
        const int r = RS + rg + 16 * it;
        if (r < 64) *(v4*)(P + r * PSTR + 4 * c4) = acc[it];
    }
    __syncthreads();
}

__global__ __launch_bounds__(256, 1) void ortho_build_R(
    const float* __restrict__ angles, const float* __restrict__ mus,
    float* __restrict__ AT_out)
{
    __shared__ float P[NPTS * PSTR];                  // M0, then running product
    __shared__ float M[3][NPTS * PSTR];               // M1, M2, M3 slabs

    const int tid  = threadIdx.x;
    const int lane = tid & 63;
    const int wv   = tid >> 6;

    if      (wv == 0) do_wave< 0,  9>(angles, P,    lane);   // 531 rotations
    else if (wv == 1) do_wave< 9, 19>(angles, M[0], lane);   // 495
    else if (wv == 2) do_wave<19, 32>(angles, M[1], lane);   // 494
    else              do_wave<32, 63>(angles, M[2], lane);   // 496
    __syncthreads();

    combine_step< 9>(P, M[0], tid);                   // P <- M1 @ P (rows 9..63)
    combine_step<19>(P, M[1], tid);                   // P <- M2 @ P (rows 19..63)
    combine_step<32>(P, M[2], tid);                   // P <- M3 @ P (rows 32..63)

    // AT[k*64 + r] = mus[r] * R[r][k]; lane = r -> coalesced 256B global stores.
    #pragma unroll
    for (int i = 0; i < 16; ++i) {
        const int idx = i * 256 + tid;                // 0..4095
        const int r   = idx & 63;
        const int k   = idx >> 6;
        AT_out[k * NPTS + r] = mus[r] * P[r * PSTR + k];
    }
}

// ---------------------------------------------------------------------------
// Kernel 2 (R10): fp32 coalesced structure (R1-proven), occupancy-fixed.
// R1 ran 1172 blocks = 4.6 waves/SIMD -> latency-bound at 52us (VALUBusy 32%,
// HBM 28%). R10: split the 4 row-groups across BLOCKS instead of waves:
// grid = 1172 col-groups x 4 row-groups = 4688 blocks; per-thread tile
// 4 rows x 1 v4-col (acc[4] + xa/xb[4] ~= 60 VGPR) -> __launch_bounds__(256,8)
// = 8 waves/SIMD resident, ~1.7x TLP. All loads/stores remain 1024B-contiguous
// per wave (dwordx4). A-table (16KB fp32) loads are wave-uniform -> L1-hot.
// ---------------------------------------------------------------------------
__global__ __launch_bounds__(256, 8) void ortho_apply(
    const float* __restrict__ X, const float* __restrict__ AT,
    float* __restrict__ Y)
{
    const int tc = threadIdx.x & 63;
    const int wv = threadIdx.x >> 6;
    const int tr = __builtin_amdgcn_readfirstlane(wv);   // wave-uniform 0..3
    const int rg = blockIdx.x & 3;                       // row-group 0..3
    const int cg = blockIdx.x >> 2;                      // col-group 0..1171
    const int r0 = rg * 16 + tr * 4;                     // this wave's 4 rows

    const int j4 = cg * 64 + tc;                         // float4 column index
    if (j4 >= NC4) return;                               // no barriers below

    const v4* xp = (const v4*)X + j4;                    // row stride NC4

    v4 acc[4];
    #pragma unroll
    for (int i = 0; i < 4; ++i) acc[i] = (v4)0.0f;

    v4 xa[4], xb[4];
    #pragma unroll
    for (int q = 0; q < 4; ++q) xa[q] = xp[q * NC4];

    for (int k0 = 0; k0 < NPTS; k0 += 8) {
        #pragma unroll
        for (int q = 0; q < 4; ++q) xb[q] = xp[(k0 + 4 + q) * NC4];
        #pragma unroll
        for (int q = 0; q < 4; ++q) {
            const v4 a = *(const v4*)(AT + (k0 + q) * NPTS + r0);   // uniform addr
            acc[0] += xa[q] * a.x;
            acc[1] += xa[q] * a.y;
            acc[2] += xa[q] * a.z;
            acc[3] += xa[q] * a.w;
        }
        #pragma unroll
        for (int q = 0; q < 4; ++q) xa[q] = xp[((k0 + 8 + q) & 63) * NC4]; // wraps last iter (harmless)
        #pragma unroll
        for (int q = 0; q < 4; ++q) {
            const v4 a = *(const v4*)(AT + (k0 + 4 + q) * NPTS + r0);
            acc[0] += xb[q] * a.x;
            acc[1] += xb[q] * a.y;
            acc[2] += xb[q] * a.z;
            acc[3] += xb[q] * a.w;
        }
    }

    #pragma unroll
    for (int i = 0; i < 4; ++i) {
        v4* yp = (v4*)(Y + (size_t)(r0 + i) * NCOLS) + j4;
        __builtin_nontemporal_store(acc[i], yp);
    }
}

// ---------------------------------------------------------------------------
extern "C" void kernel_launch(void* const* d_in, const int* in_sizes, int n_in,
                              void* d_out, int out_size, void* d_ws, size_t ws_size,
                              hipStream_t stream) {
    const float* X      = (const float*)d_in[0];   // 64 x 300000
    const float* angles = (const float*)d_in[1];   // 2016
    const float* mus    = (const float*)d_in[2];   // 64
    float* Y  = (float*)d_out;                     // 64 x 300000
    float* AT = (float*)d_ws;                      // 64 x 64 fp32 scratch

    ortho_build_R<<<1, 256, 0, stream>>>(angles, mus, AT);

    const int nblk = ((NC4 + 63) / 64) * 4;        // 1172 col-groups x 4 row-groups
    ortho_apply<<<nblk, 256, 0, stream>>>(X, AT, Y);
}

// Round 7
// 198.370 us; speedup vs baseline: 1.1579x; 1.1579x over previous
//
#include <hip/hip_runtime.h>

#define NPTS  64
#define NANG  2016          // 64*63/2
#define NCOLS 300000
#define NC4   (NCOLS / 4)   // 75000 float4 columns

typedef float v4 __attribute__((ext_vector_type(4)));

#define PSTR 68             // LDS row stride in floats: 16B-aligned (68*4=272=17*16)

// ---------------------------------------------------------------------------
// Kernel 1: build A^T (mus folded) into d_ws as AT[k*64 + row] = mus[row]*R[row][k]
// (fp32). BYTE-IDENTICAL to the R10 build (passed R3/R5/R6) — this round
// changes only ortho_apply, so build_R's true duration finally shows in the
// top-5 (R11 apply should drop to ~25us, below build's inferred ~47us).
// ---------------------------------------------------------------------------

__device__ __forceinline__ float rl(float x, int lane) {
    return __uint_as_float(__builtin_amdgcn_readlane(__float_as_uint(x), lane));
}

// Groups T..TB-1, exact length 63-T each. S[j] = running[row T+j][col lane].
// Rotation i (1-based) of group T: rows (T, T+i); lane i-1 holds its (c,s).
template<int T, int TB, int TA, int NG>
__device__ __forceinline__ void groups_run(float (&S)[NPTS],
                                           const float (&c)[NG], const float (&s)[NG],
                                           float* __restrict__ slab, int lane)
{
    if constexpr (T < TB) {
        constexpr int g   = T - TA;
        constexpr int LEN = 63 - T;                   // real rotations in group T
        float rt = S[0];
        #pragma unroll
        for (int i = 1; i <= LEN; ++i) {              // compile-time i
            const float cc = rl(c[g], i - 1);         // v_readlane, imm lane
            const float ss = rl(s[g], i - 1);
            const float rb = S[i];
            S[i - 1] = fmaf(ss, rt, cc * rb);         // new row (T+i), pre-shifted
            rt       = fmaf(cc, rt, -ss * rb);        // serial chain
        }
        slab[T * PSTR + lane] = rt;                   // row T of Mw finished
        groups_run<T + 1, TB, TA, NG>(S, c, s, slab, lane);
    }
}

template<int TA, int TB>
__device__ __forceinline__ void do_wave(const float* __restrict__ angles,
                                        float* __restrict__ slab, int lane)
{
    constexpr int NG = TB - TA;
    float c[NG], s[NG];
    #pragma unroll
    for (int g = 0; g < NG; ++g) {                    // all independent -> pipelined
        const int t    = TA + g;
        const int base = 63 * t - (t * (t - 1)) / 2;  // angle base of group t
        float a = 0.0f;
        if (lane < 63 - t) a = angles[base + lane];   // lane i-1 <-> rotation i
        float sv, cv;
        sincosf(a, &sv, &cv);                         // scalar temps: outputs stay
        s[g] = sv; c[g] = cv;                         // promotable to registers
    }

    // segment starts from identity restricted to rows TA..TA+63 (cols<TA: all 0)
    float S[NPTS];
    #pragma unroll
    for (int j = 0; j < NPTS; ++j) S[j] = (TA + j == lane) ? 1.0f : 0.0f;

    groups_run<TA, TB, TA, NG>(S, c, s, slab, lane);

    // rows TB..63 of Mw still live in S[0..63-TB]
    #pragma unroll
    for (int j = 0; j <= 63 - TB; ++j)
        slab[(TB + j) * PSTR + lane] = S[j];
}

// P[rows >= RS] = Ms[RS: , RS:] @ P[RS: , :]; rows < RS of P unchanged.
// k4 starts at RS/4: Ms cols < RS are exact zeros, so partial quads are safe.
template<int RS>
__device__ __forceinline__ void combine_step(float* __restrict__ P,
                                             const float* __restrict__ Ms,
                                             int tid)
{
    const int c4 = tid & 15;                          // v4 column 0..15
    const int rg = tid >> 4;                          // row group 0..15
    constexpr int NR   = 64 - RS;
    constexpr int NIT  = (NR + 15) / 16;
    constexpr int K4_0 = RS / 4;

    v4 acc[NIT];
    #pragma unroll
    for (int it = 0; it < NIT; ++it) acc[it] = (v4)0.0f;

    #pragma unroll 2
    for (int k4 = K4_0; k4 < 16; ++k4) {
        v4 pv[4];
        #pragma unroll
        for (int j = 0; j < 4; ++j)                   // same addr across lanes-of-16:
            pv[j] = *(const v4*)(P + (4 * k4 + j) * PSTR + 4 * c4);   // broadcast
        #pragma unroll
        for (int it = 0; it < NIT; ++it) {
            const int r = RS + rg + 16 * it;
            if (r < 64) {
                const v4 mv = *(const v4*)(Ms + r * PSTR + 4 * k4);
                acc[it] += pv[0] * mv.x;
                acc[it] += pv[1] * mv.y;
                acc[it] += pv[2] * mv.z;
                acc[it] += pv[3] * mv.w;
            }
        }
    }
    __syncthreads();                                  // all reads of P done
    #pragma unroll
    for (int it = 0; it < NIT; ++it) {
        const int r = RS + rg + 16 * it;
        if (r < 64) *(v4*)(P + r * PSTR + 4 * c4) = acc[it];
    }
    __syncthreads();
}

__global__ __launch_bounds__(256, 1) void ortho_build_R(
    const float* __restrict__ angles, const float* __restrict__ mus,
    float* __restrict__ AT_out)
{
    __shared__ float P[NPTS * PSTR];                  // M0, then running product
    __shared__ float M[3][NPTS * PSTR];               // M1, M2, M3 slabs

    const int tid  = threadIdx.x;
    const int lane = tid & 63;
    const int wv   = tid >> 6;

    if      (wv == 0) do_wave< 0,  9>(angles, P,    lane);   // 531 rotations
    else if (wv == 1) do_wave< 9, 19>(angles, M[0], lane);   // 495
    else if (wv == 2) do_wave<19, 32>(angles, M[1], lane);   // 494
    else              do_wave<32, 63>(angles, M[2], lane);   // 496
    __syncthreads();

    combine_step< 9>(P, M[0], tid);                   // P <- M1 @ P (rows 9..63)
    combine_step<19>(P, M[1], tid);                   // P <- M2 @ P (rows 19..63)
    combine_step<32>(P, M[2], tid);                   // P <- M3 @ P (rows 32..63)

    // AT[k*64 + r] = mus[r] * R[r][k]; lane = r -> coalesced 256B global stores.
    #pragma unroll
    for (int i = 0; i < 16; ++i) {
        const int idx = i * 256 + tid;                // 0..4095
        const int r   = idx & 63;
        const int k   = idx >> 6;
        AT_out[k * NPTS + r] = mus[r] * P[r * PSTR + k];
    }
}

// ---------------------------------------------------------------------------
// Kernel 2 (R11): R1's proven memory pattern (block owns all 64 rows -> X read
// once; 1024B-coalesced loads/stores; 1172 blocks x 4 waves x 16 rows) with
// the in-loop AT loads REMOVED from the dependency path:
//   - prologue: lane l loads A[r0..r0+15][k=l] as 4 v4 (16 VGPR) -- the whole
//     A panel for this wave lives in the register file;
//   - k-loop: a-values broadcast by v_readlane (SGPR lane index = runtime
//     uniform k; register-file op, zero memory latency); 64 fma + 16 readlane
//     per k; outer k0-loop kept ROLLED (body ~6KB, i-cache safe).
// R6/R10 post-mortems: row-split blocks 4x'd FETCH (150MB) -> must keep
// 64-row blocks; R1's 52us vs ~17us compute floor was AT-load latency in the
// critical path (VALUBusy 32%). Predicted: ~21-27us, VALUBusy 55-75%,
// FETCH ~39MB, WRITE 75MB.
// No divergent exit: last block's 8 overhanging lanes clamp to column 74999
// (benign duplicate compute/store of identical values) so no early-return
// sits above the readlanes (readlane ignores exec).
// ---------------------------------------------------------------------------
__global__ __launch_bounds__(256) void ortho_apply(
    const float* __restrict__ X, const float* __restrict__ AT,
    float* __restrict__ Y)
{
    const int tc = threadIdx.x & 63;                     // lane
    const int wv = threadIdx.x >> 6;
    const int tr = __builtin_amdgcn_readfirstlane(wv);   // wave-uniform 0..3
    const int r0 = tr * 16;                              // this wave's 16 rows

    int j4 = blockIdx.x * 64 + tc;                       // float4 column index
    if (j4 >= NC4) j4 = NC4 - 1;                         // benign clamp (8 lanes max)

    // lane l holds A[r0 + 0..15][k = l]: av[j][c] = AT[l*64 + r0 + 4j + c]
    v4 av[4];
    #pragma unroll
    for (int j = 0; j < 4; ++j)
        av[j] = *(const v4*)(AT + tc * NPTS + r0 + 4 * j);

    const v4* xp = (const v4*)X + j4;                    // row stride NC4

    v4 acc[16];
    #pragma unroll
    for (int i = 0; i < 16; ++i) acc[i] = (v4)0.0f;

    v4 xa[4], xb[4];
    #pragma unroll
    for (int q = 0; q < 4; ++q) xa[q] = xp[q * NC4];

    for (int k0 = 0; k0 < NPTS; k0 += 8) {               // rolled: 8 iterations
        #pragma unroll
        for (int q = 0; q < 4; ++q) xb[q] = xp[(k0 + 4 + q) * NC4];
        #pragma unroll
        for (int kk = 0; kk < 4; ++kk) {
            const int k = k0 + kk;                       // runtime uniform (SGPR)
            #pragma unroll
            for (int r = 0; r < 16; ++r) {
                const float a = rl(av[r >> 2][r & 3], k);   // v_readlane -> SGPR
                acc[r] += xa[kk] * a;                       // v_fma, 1 SGPR operand
            }
        }
        #pragma unroll
        for (int q = 0; q < 4; ++q) xa[q] = xp[((k0 + 8 + q) & 63) * NC4]; // wraps last iter (harmless)
        #pragma unroll
        for (int kk = 0; kk < 4; ++kk) {
            const int k = k0 + 4 + kk;
            #pragma unroll
            for (int r = 0; r < 16; ++r) {
                const float a = rl(av[r >> 2][r & 3], k);
                acc[r] += xb[kk] * a;
            }
        }
    }

    #pragma unroll
    for (int i = 0; i < 16; ++i) {
        v4* yp = (v4*)(Y + (size_t)(r0 + i) * NCOLS) + j4;
        __builtin_nontemporal_store(acc[i], yp);
    }
}

// ---------------------------------------------------------------------------
extern "C" void kernel_launch(void* const* d_in, const int* in_sizes, int n_in,
                              void* d_out, int out_size, void* d_ws, size_t ws_size,
                              hipStream_t stream) {
    const float* X      = (const float*)d_in[0];   // 64 x 300000
    const float* angles = (const float*)d_in[1];   // 2016
    const float* mus    = (const float*)d_in[2];   // 64
    float* Y  = (float*)d_out;                     // 64 x 300000
    float* AT = (float*)d_ws;                      // 64 x 64 fp32 scratch

    ortho_build_R<<<1, 256, 0, stream>>>(angles, mus, AT);

    const int nblk = (NC4 + 63) / 64;              // 1172 column chunks
    ortho_apply<<<nblk, 256, 0, stream>>>(X, AT, Y);
}

// Round 8
// 176.171 us; speedup vs baseline: 1.3038x; 1.1260x over previous
//
#include <hip/hip_runtime.h>

#define NPTS  64
#define NANG  2016          // 64*63/2
#define NCOLS 300000
#define NC4   (NCOLS / 4)   // 75000 float4 columns

typedef float v4 __attribute__((ext_vector_type(4)));

#define PSTR 68             // LDS row stride in floats: 16B-aligned (68*4=272=17*16)

// ---------------------------------------------------------------------------
// Kernel 1 (R12): I-CACHE-SIZED build.
// Evidence: build+overhead ~= 139us across R1/R3/R5/R6/R7 whether build was
// 1-wave (R1) or 4-wave segmented (R3+) -> build ~= 47-48us BOTH ways. Both
// variants unroll ~2.5k rotations = ~115KB straight-line code >> 32KB I$ ->
// instruction-fetch bound (~8cyc/instr), wave-parallelism invariant.
// Fix: ROLL the outer group loop; pad every group to 63 rotations (identity
// pads are fp-exact no-ops: c=1,s=0 -> S[i-1]=rb, rt=rt). One ~2.8KB body.
// Segments rebalanced to equal GROUP counts {0,16,32,48,63} (16/16/16/15).
// Inner 63-step shift register stays fully unrolled (compile-time S indices,
// imm-lane readlane). Tail rows written via compile-time per-wave switch.
// Combine (proven R3/R5/R6/R7 structure) at quad-aligned RS = 16/32/48.
// ---------------------------------------------------------------------------

__device__ __forceinline__ float rl(float x, int lane) {
    return __uint_as_float(__builtin_amdgcn_readlane(__float_as_uint(x), lane));
}

// angle for rotation (t, t+lane+1); clamped in-bounds for pipeline overrun
__device__ __forceinline__ float load_ang(const float* __restrict__ angles,
                                          int t, int lane) {
    int base = 63 * t - (t * (t - 1)) / 2;   // t <= 64 -> no overflow
    int idx  = base + lane;
    idx = idx < NANG ? idx : NANG - 1;
    return angles[idx];
}

// (c,s) for group t; identity (1,0) for padded lanes (lane >= 63-t)
__device__ __forceinline__ void make_cs(float a, int t, int lane,
                                        float& c, float& s) {
    const int real = 63 - t;
    const float ang = (lane < real) ? a : 0.0f;   // sincosf(0) -> (1,0)
    float sv, cv;
    sincosf(ang, &sv, &cv);
    s = sv; c = cv;
}

// P[rows >= RS] = Ms[RS:, RS:] @ P[RS:, :]; rows < RS of P unchanged.
// k4 starts at RS/4: Ms cols < RS are exact zeros by construction.
template<int RS>
__device__ __forceinline__ void combine_step(float* __restrict__ P,
                                             const float* __restrict__ Ms,
                                             int tid)
{
    const int c4 = tid & 15;                          // v4 column 0..15
    const int rg = tid >> 4;                          // row group 0..15
    constexpr int NR   = 64 - RS;
    constexpr int NIT  = (NR + 15) / 16;
    constexpr int K4_0 = RS / 4;

    v4 acc[NIT];
    #pragma unroll
    for (int it = 0; it < NIT; ++it) acc[it] = (v4)0.0f;

    #pragma unroll 2
    for (int k4 = K4_0; k4 < 16; ++k4) {
        v4 pv[4];
        #pragma unroll
        for (int j = 0; j < 4; ++j)                   // same addr across lanes-of-16:
            pv[j] = *(const v4*)(P + (4 * k4 + j) * PSTR + 4 * c4);   // broadcast
        #pragma unroll
        for (int it = 0; it < NIT; ++it) {
            const int r = RS + rg + 16 * it;          // RS=16: 16..63 all valid
            const v4 mv = *(const v4*)(Ms + r * PSTR + 4 * k4);
            acc[it] += pv[0] * mv.x;
            acc[it] += pv[1] * mv.y;
            acc[it] += pv[2] * mv.z;
            acc[it] += pv[3] * mv.w;
        }
    }
    __syncthreads();                                  // all reads of P done
    #pragma unroll
    for (int it = 0; it < NIT; ++it) {
        const int r = RS + rg + 16 * it;
        *(v4*)(P + r * PSTR + 4 * c4) = acc[it];
    }
    __syncthreads();
}

__global__ __launch_bounds__(256, 1) void ortho_build_R(
    const float* __restrict__ angles, const float* __restrict__ mus,
    float* __restrict__ AT_out)
{
    __shared__ float P[NPTS * PSTR];                  // M0, then running product
    __shared__ float M[3][NPTS * PSTR];               // M1, M2, M3 slabs

    const int tid  = threadIdx.x;
    const int lane = tid & 63;
    const int wv   = tid >> 6;

    float* slab = (wv == 0) ? P : M[wv - 1];
    const int TA = 16 * wv;                           // groups [TA, TB)
    const int TB = (wv == 3) ? 63 : TA + 16;          // 16/16/16/15 groups

    // S[j] = running segment row (t + j), col = lane. Compile-time indices only.
    float S[64];
    #pragma unroll
    for (int j = 0; j < 64; ++j) S[j] = (TA + j == lane) ? 1.0f : 0.0f;

    // software pipeline: (c0,s0) for group t, a1 = angle for group t+1
    float c0, s0;
    {
        const float a0 = load_ang(angles, TA, lane);
        make_cs(a0, TA, lane, c0, s0);
    }
    float a1 = load_ang(angles, TA + 1, lane);

    #pragma clang loop unroll(disable)
    for (int t = TA; t < TB; ++t) {                   // ROLLED: one 2.8KB body
        const float a2 = load_ang(angles, t + 2, lane);
        float c1, s1;
        make_cs(a1, t + 1, lane, c1, s1);

        float rt = S[0];
        #pragma unroll
        for (int i = 1; i <= 63; ++i) {               // compile-time i
            const float cc = rl(c0, i - 1);           // v_readlane, imm lane
            const float ss = rl(s0, i - 1);
            const float rb = S[i];
            S[i - 1] = fmaf(ss, rt, cc * rb);         // new row (t+i), pre-shifted
            rt       = fmaf(cc, rt, -ss * rb);        // serial chain
        }
        slab[t * PSTR + lane] = rt;                   // row t finished

        c0 = c1; s0 = s1; a1 = a2;
    }

    // tail: rows TB..63 live in S[0..63-TB]; compile-time indices per wave
    if (wv == 0) {
        #pragma unroll
        for (int j = 0; j < 48; ++j) slab[(16 + j) * PSTR + lane] = S[j];
    } else if (wv == 1) {
        #pragma unroll
        for (int j = 0; j < 32; ++j) slab[(32 + j) * PSTR + lane] = S[j];
    } else if (wv == 2) {
        #pragma unroll
        for (int j = 0; j < 16; ++j) slab[(48 + j) * PSTR + lane] = S[j];
    } else {
        slab[63 * PSTR + lane] = S[0];
    }
    __syncthreads();

    combine_step<16>(P, M[0], tid);                   // P <- M1 @ P (rows 16..63)
    combine_step<32>(P, M[1], tid);                   // P <- M2 @ P (rows 32..63)
    combine_step<48>(P, M[2], tid);                   // P <- M3 @ P (rows 48..63)

    // AT[k*64 + r] = mus[r] * R[r][k]; lane = r -> coalesced 256B global stores.
    #pragma unroll
    for (int i = 0; i < 16; ++i) {
        const int idx = i * 256 + tid;                // 0..4095
        const int r   = idx & 63;
        const int k   = idx >> 6;
        AT_out[k * NPTS + r] = mus[r] * P[r * PSTR + k];
    }
}

// ---------------------------------------------------------------------------
// Kernel 2 (R12): R1's proven memory pattern (block owns all 64 rows -> X read
// once; 1024B-coalesced dwordx4 loads/stores; xa/xb double-buffer; uniform
// s_load AT reads) with ONE change: 8 waves x 8 rows instead of 4 x 16.
// R7 post-mortem: readlane broadcast added VALU ops and regressed (59 vs 52);
// R1's residual gap to the ~20us floor is TLP (grid 4688 waves = 18.3/CU max,
// measured occupancy 24.6%). 512-thread blocks double wave count to 9376 and
// halve acc to 32 VGPR -> up to 32 resident waves/CU. X loads unchanged
// (8x intra-block redundancy absorbed by L1/L2, HBM traffic identical).
// ---------------------------------------------------------------------------
__global__ __launch_bounds__(512) void ortho_apply(
    const float* __restrict__ X, const float* __restrict__ AT,
    float* __restrict__ Y)
{
    const int tc = threadIdx.x & 63;
    const int wv = threadIdx.x >> 6;
    const int tr = __builtin_amdgcn_readfirstlane(wv);   // wave-uniform 0..7
    const int r0 = tr * 8;                               // this wave's 8 rows

    const int j4 = blockIdx.x * 64 + tc;                 // float4 column index
    if (j4 >= NC4) return;                               // no barriers below

    const v4* xp = (const v4*)X + j4;                    // row stride NC4

    v4 acc[8];
    #pragma unroll
    for (int i = 0; i < 8; ++i) acc[i] = (v4)0.0f;

    v4 xa[4], xb[4];
    #pragma unroll
    for (int q = 0; q < 4; ++q) xa[q] = xp[q * NC4];

    for (int k0 = 0; k0 < NPTS; k0 += 8) {
        #pragma unroll
        for (int q = 0; q < 4; ++q) xb[q] = xp[(k0 + 4 + q) * NC4];
        #pragma unroll
        for (int q = 0; q < 4; ++q) {
            const v4 a  = *(const v4*)(AT + (k0 + q) * NPTS + r0);      // uniform
            const v4 a2 = *(const v4*)(AT + (k0 + q) * NPTS + r0 + 4);  // uniform
            acc[0] += xa[q] * a.x;  acc[1] += xa[q] * a.y;
            acc[2] += xa[q] * a.z;  acc[3] += xa[q] * a.w;
            acc[4] += xa[q] * a2.x; acc[5] += xa[q] * a2.y;
            acc[6] += xa[q] * a2.z; acc[7] += xa[q] * a2.w;
        }
        #pragma unroll
        for (int q = 0; q < 4; ++q) xa[q] = xp[((k0 + 8 + q) & 63) * NC4]; // wraps last iter (harmless)
        #pragma unroll
        for (int q = 0; q < 4; ++q) {
            const v4 a  = *(const v4*)(AT + (k0 + 4 + q) * NPTS + r0);
            const v4 a2 = *(const v4*)(AT + (k0 + 4 + q) * NPTS + r0 + 4);
            acc[0] += xb[q] * a.x;  acc[1] += xb[q] * a.y;
            acc[2] += xb[q] * a.z;  acc[3] += xb[q] * a.w;
            acc[4] += xb[q] * a2.x; acc[5] += xb[q] * a2.y;
            acc[6] += xb[q] * a2.z; acc[7] += xb[q] * a2.w;
        }
    }

    #pragma unroll
    for (int i = 0; i < 8; ++i) {
        v4* yp = (v4*)(Y + (size_t)(r0 + i) * NCOLS) + j4;
        __builtin_nontemporal_store(acc[i], yp);
    }
}

// ---------------------------------------------------------------------------
extern "C" void kernel_launch(void* const* d_in, const int* in_sizes, int n_in,
                              void* d_out, int out_size, void* d_ws, size_t ws_size,
                              hipStream_t stream) {
    const float* X      = (const float*)d_in[0];   // 64 x 300000
    const float* angles = (const float*)d_in[1];   // 2016
    const float* mus    = (const float*)d_in[2];   // 64
    float* Y  = (float*)d_out;                     // 64 x 300000
    float* AT = (float*)d_ws;                      // 64 x 64 fp32 scratch

    ortho_build_R<<<1, 256, 0, stream>>>(angles, mus, AT);

    const int nblk = (NC4 + 63) / 64;              // 1172 column chunks
    ortho_apply<<<nblk, 512, 0, stream>>>(X, AT, Y);
}

// Round 9
// 167.541 us; speedup vs baseline: 1.3709x; 1.0515x over previous
//
#include <hip/hip_runtime.h>

#define NPTS  64
#define NANG  2016          // 64*63/2
#define NCOLS 300000
#define NC4   (NCOLS / 4)   // 75000 float4 columns

typedef float v4 __attribute__((ext_vector_type(4)));

#define PSTR 68             // LDS row stride in floats: 16B-aligned (68*4=272=17*16)

// ---------------------------------------------------------------------------
// Kernel 1: BYTE-IDENTICAL to R12 build (I-cache-sized, rolled outer loop).
// R12 arithmetic: build ~= 23us (total 176.2 - apply 62.5 - overhead 91).
// I-fetch theory confirmed (47 -> 23 by shrinking code 115KB -> ~3KB body).
// Unchanged this round for attribution.
// ---------------------------------------------------------------------------

__device__ __forceinline__ float rl(float x, int lane) {
    return __uint_as_float(__builtin_amdgcn_readlane(__float_as_uint(x), lane));
}

// angle for rotation (t, t+lane+1); clamped in-bounds for pipeline overrun
__device__ __forceinline__ float load_ang(const float* __restrict__ angles,
                                          int t, int lane) {
    int base = 63 * t - (t * (t - 1)) / 2;   // t <= 64 -> no overflow
    int idx  = base + lane;
    idx = idx < NANG ? idx : NANG - 1;
    return angles[idx];
}

// (c,s) for group t; identity (1,0) for padded lanes (lane >= 63-t)
__device__ __forceinline__ void make_cs(float a, int t, int lane,
                                        float& c, float& s) {
    const int real = 63 - t;
    const float ang = (lane < real) ? a : 0.0f;   // sincosf(0) -> (1,0)
    float sv, cv;
    sincosf(ang, &sv, &cv);
    s = sv; c = cv;
}

// P[rows >= RS] = Ms[RS:, RS:] @ P[RS:, :]; rows < RS of P unchanged.
// k4 starts at RS/4: Ms cols < RS are exact zeros by construction.
template<int RS>
__device__ __forceinline__ void combine_step(float* __restrict__ P,
                                             const float* __restrict__ Ms,
                                             int tid)
{
    const int c4 = tid & 15;                          // v4 column 0..15
    const int rg = tid >> 4;                          // row group 0..15
    constexpr int NR   = 64 - RS;
    constexpr int NIT  = (NR + 15) / 16;
    constexpr int K4_0 = RS / 4;

    v4 acc[NIT];
    #pragma unroll
    for (int it = 0; it < NIT; ++it) acc[it] = (v4)0.0f;

    #pragma unroll 2
    for (int k4 = K4_0; k4 < 16; ++k4) {
        v4 pv[4];
        #pragma unroll
        for (int j = 0; j < 4; ++j)                   // same addr across lanes-of-16:
            pv[j] = *(const v4*)(P + (4 * k4 + j) * PSTR + 4 * c4);   // broadcast
        #pragma unroll
        for (int it = 0; it < NIT; ++it) {
            const int r = RS + rg + 16 * it;
            const v4 mv = *(const v4*)(Ms + r * PSTR + 4 * k4);
            acc[it] += pv[0] * mv.x;
            acc[it] += pv[1] * mv.y;
            acc[it] += pv[2] * mv.z;
            acc[it] += pv[3] * mv.w;
        }
    }
    __syncthreads();                                  // all reads of P done
    #pragma unroll
    for (int it = 0; it < NIT; ++it) {
        const int r = RS + rg + 16 * it;
        *(v4*)(P + r * PSTR + 4 * c4) = acc[it];
    }
    __syncthreads();
}

__global__ __launch_bounds__(256, 1) void ortho_build_R(
    const float* __restrict__ angles, const float* __restrict__ mus,
    float* __restrict__ AT_out)
{
    __shared__ float P[NPTS * PSTR];                  // M0, then running product
    __shared__ float M[3][NPTS * PSTR];               // M1, M2, M3 slabs

    const int tid  = threadIdx.x;
    const int lane = tid & 63;
    const int wv   = tid >> 6;

    float* slab = (wv == 0) ? P : M[wv - 1];
    const int TA = 16 * wv;                           // groups [TA, TB)
    const int TB = (wv == 3) ? 63 : TA + 16;          // 16/16/16/15 groups

    // S[j] = running segment row (t + j), col = lane. Compile-time indices only.
    float S[64];
    #pragma unroll
    for (int j = 0; j < 64; ++j) S[j] = (TA + j == lane) ? 1.0f : 0.0f;

    // software pipeline: (c0,s0) for group t, a1 = angle for group t+1
    float c0, s0;
    {
        const float a0 = load_ang(angles, TA, lane);
        make_cs(a0, TA, lane, c0, s0);
    }
    float a1 = load_ang(angles, TA + 1, lane);

    #pragma clang loop unroll(disable)
    for (int t = TA; t < TB; ++t) {                   // ROLLED: one ~3KB body
        const float a2 = load_ang(angles, t + 2, lane);
        float c1, s1;
        make_cs(a1, t + 1, lane, c1, s1);

        float rt = S[0];
        #pragma unroll
        for (int i = 1; i <= 63; ++i) {               // compile-time i
            const float cc = rl(c0, i - 1);           // v_readlane, imm lane
            const float ss = rl(s0, i - 1);
            const float rb = S[i];
            S[i - 1] = fmaf(ss, rt, cc * rb);         // new row (t+i), pre-shifted
            rt       = fmaf(cc, rt, -ss * rb);        // serial chain
        }
        slab[t * PSTR + lane] = rt;                   // row t finished

        c0 = c1; s0 = s1; a1 = a2;
    }

    // tail: rows TB..63 live in S[0..63-TB]; compile-time indices per wave
    if (wv == 0) {
        #pragma unroll
        for (int j = 0; j < 48; ++j) slab[(16 + j) * PSTR + lane] = S[j];
    } else if (wv == 1) {
        #pragma unroll
        for (int j = 0; j < 32; ++j) slab[(32 + j) * PSTR + lane] = S[j];
    } else if (wv == 2) {
        #pragma unroll
        for (int j = 0; j < 16; ++j) slab[(48 + j) * PSTR + lane] = S[j];
    } else {
        slab[63 * PSTR + lane] = S[0];
    }
    __syncthreads();

    combine_step<16>(P, M[0], tid);                   // P <- M1 @ P (rows 16..63)
    combine_step<32>(P, M[1], tid);                   // P <- M2 @ P (rows 32..63)
    combine_step<48>(P, M[2], tid);                   // P <- M3 @ P (rows 48..63)

    // AT[k*64 + r] = mus[r] * R[r][k]; lane = r -> coalesced 256B global stores.
    #pragma unroll
    for (int i = 0; i < 16; ++i) {
        const int idx = i * 256 + tid;                // 0..4095
        const int r   = idx & 63;
        const int k   = idx >> 6;
        AT_out[k * NPTS + r] = mus[r] * P[r * PSTR + k];
    }
}

// ---------------------------------------------------------------------------
// Kernel 2 (R13): ZERO-REDUNDANCY column ownership.
// R12 post-mortem: occupancy 24.6->43% yet dur 52->62us, VALUBusy 27%, BW
// down -- each added wave re-read all 64 X rows (8x intra-block redundancy),
// L1/L2 contention ate the TLP. R10: row-split blocks 4x'd HBM FETCH.
// Conclusion: a wave must own COLUMNS exclusively and compute ALL 64 rows.
//   - lane owns 1 scalar column; acc[64] floats = 64 VGPR (compile-time idx);
//   - X: one coalesced dword load per (k, wave) -- each X byte read ONCE
//     per chip (L1/L2 read traffic 4x lower than R1, HBM unchanged);
//   - A: wave-uniform v4 reads (s_load -> SGPR operand in v_fma, 1/instr);
//   - per k: 1 load + 64 independent fma = deep ILP; ~80 VGPR -> 16+
//     waves/CU resident; xa/xb 4-deep double-buffer (R1-proven pattern).
// Same grid (1172 x 256), same per-element k-order (absmax identical).
// Last block: 32 overhang lanes clamp to col 299999 (duplicate identical
// stores, no divergent return).
// ---------------------------------------------------------------------------
__global__ __launch_bounds__(256) void ortho_apply(
    const float* __restrict__ X, const float* __restrict__ AT,
    float* __restrict__ Y)
{
    const int lane = threadIdx.x & 63;
    const int wv   = threadIdx.x >> 6;
    int col = blockIdx.x * 256 + wv * 64 + lane;     // this lane's column
    if (col >= NCOLS) col = NCOLS - 1;               // benign clamp (last block)

    const float* xp = X + col;
    const v4* ATv = (const v4*)AT;                   // ATv[k*16+rq] = rows 4rq..4rq+3 @ col k

    float acc[64];
    #pragma unroll
    for (int r = 0; r < 64; ++r) acc[r] = 0.0f;

    float xa[4], xb[4];
    #pragma unroll
    for (int q = 0; q < 4; ++q) xa[q] = xp[(size_t)q * NCOLS];

    for (int k0 = 0; k0 < NPTS; k0 += 8) {           // rolled: 8 iterations
        #pragma unroll
        for (int q = 0; q < 4; ++q) xb[q] = xp[(size_t)(k0 + 4 + q) * NCOLS];
        #pragma unroll
        for (int kk = 0; kk < 4; ++kk) {
            const int k = k0 + kk;
            #pragma unroll
            for (int rq = 0; rq < 16; ++rq) {
                const v4 a = ATv[k * 16 + rq];       // wave-uniform -> s_load
                acc[4 * rq + 0] += xa[kk] * a.x;
                acc[4 * rq + 1] += xa[kk] * a.y;
                acc[4 * rq + 2] += xa[kk] * a.z;
                acc[4 * rq + 3] += xa[kk] * a.w;
            }
        }
        #pragma unroll
        for (int q = 0; q < 4; ++q) xa[q] = xp[(size_t)((k0 + 8 + q) & 63) * NCOLS]; // wraps last iter (harmless)
        #pragma unroll
        for (int kk = 0; kk < 4; ++kk) {
            const int k = k0 + 4 + kk;
            #pragma unroll
            for (int rq = 0; rq < 16; ++rq) {
                const v4 a = ATv[k * 16 + rq];
                acc[4 * rq + 0] += xb[kk] * a.x;
                acc[4 * rq + 1] += xb[kk] * a.y;
                acc[4 * rq + 2] += xb[kk] * a.z;
                acc[4 * rq + 3] += xb[kk] * a.w;
            }
        }
    }

    #pragma unroll
    for (int r = 0; r < 64; ++r)
        __builtin_nontemporal_store(acc[r], Y + (size_t)r * NCOLS + col);
}

// ---------------------------------------------------------------------------
extern "C" void kernel_launch(void* const* d_in, const int* in_sizes, int n_in,
                              void* d_out, int out_size, void* d_ws, size_t ws_size,
                              hipStream_t stream) {
    const float* X      = (const float*)d_in[0];   // 64 x 300000
    const float* angles = (const float*)d_in[1];   // 2016
    const float* mus    = (const float*)d_in[2];   // 64
    float* Y  = (float*)d_out;                     // 64 x 300000
    float* AT = (float*)d_ws;                      // 64 x 64 fp32 scratch

    ortho_build_R<<<1, 256, 0, stream>>>(angles, mus, AT);

    const int nblk = (NCOLS + 255) / 256;          // 1172 column blocks
    ortho_apply<<<nblk, 256, 0, stream>>>(X, AT, Y);
}